// Round 1
// baseline (918.956 us; speedup 1.0000x reference)
//
#include <hip/hip_runtime.h>

#define N_NODES 50000
#define N_EDGES 800000
#define NREL 8
#define KSTEPS 36            // 1152 / 32
#define A_STRIDE 1160        // bf16 elements per LDS row: 1152 + 8 pad -> 580 dwords, %32==4

typedef __attribute__((ext_vector_type(8))) short short8;
typedef __attribute__((ext_vector_type(4))) float f32x4;

__device__ __forceinline__ unsigned short f2bf(float v) {
    union { float f; unsigned int u; } c; c.f = v;
    // round-to-nearest-even fp32 -> bf16
    return (unsigned short)((c.u + 0x7FFFu + ((c.u >> 16) & 1u)) >> 16);
}

// ---------------------------------------------------------------------------
// CSR construction
// ---------------------------------------------------------------------------
__global__ void count_kernel(const int* __restrict__ ei, const int* __restrict__ et,
                             int* __restrict__ deg, int* __restrict__ cnt, int E) {
    int e = blockIdx.x * blockDim.x + threadIdx.x;
    if (e >= E) return;
    int d = ei[E + e];      // dst row of edge_index
    int t = et[e];
    atomicAdd(&deg[d], 1);
    atomicAdd(&cnt[d * NREL + t], 1);
}

__global__ void scan_kernel(const int* __restrict__ deg, int* __restrict__ rowstart,
                            int* __restrict__ cursor, int N, int E) {
    __shared__ int buf[1024];
    __shared__ int carry_s;
    int tid = threadIdx.x;
    if (tid == 0) carry_s = 0;
    __syncthreads();
    for (int base = 0; base < N; base += 4096) {
        int i0 = base + tid * 4;
        int v0 = (i0 + 0 < N) ? deg[i0 + 0] : 0;
        int v1 = (i0 + 1 < N) ? deg[i0 + 1] : 0;
        int v2 = (i0 + 2 < N) ? deg[i0 + 2] : 0;
        int v3 = (i0 + 3 < N) ? deg[i0 + 3] : 0;
        int s = v0 + v1 + v2 + v3;
        buf[tid] = s;
        __syncthreads();
        for (int off = 1; off < 1024; off <<= 1) {
            int t = (tid >= off) ? buf[tid - off] : 0;
            __syncthreads();
            buf[tid] += t;
            __syncthreads();
        }
        int excl = buf[tid] - s;          // exclusive prefix of this thread's chunk
        int carry = carry_s;
        int b = carry + excl;
        if (i0 + 0 < N) { rowstart[i0 + 0] = b;              cursor[i0 + 0] = b; }
        if (i0 + 1 < N) { rowstart[i0 + 1] = b + v0;         cursor[i0 + 1] = b + v0; }
        if (i0 + 2 < N) { rowstart[i0 + 2] = b + v0 + v1;    cursor[i0 + 2] = b + v0 + v1; }
        if (i0 + 3 < N) { rowstart[i0 + 3] = b + v0 + v1 + v2; cursor[i0 + 3] = b + v0 + v1 + v2; }
        int total = buf[1023];
        __syncthreads();
        if (tid == 0) carry_s = carry + total;
        __syncthreads();
    }
    if (tid == 0) rowstart[N] = E;
}

__global__ void scatter_kernel(const int* __restrict__ ei, const int* __restrict__ et,
                               const int* __restrict__ cnt, int* __restrict__ cursor,
                               int* __restrict__ csr_st, float* __restrict__ csr_w, int E) {
    int e = blockIdx.x * blockDim.x + threadIdx.x;
    if (e >= E) return;
    int s = ei[e];
    int d = ei[E + e];
    int t = et[e];
    int pos = atomicAdd(&cursor[d], 1);
    csr_st[pos] = s | (t << 24);
    int c = cnt[d * NREL + t];           // >= 1 here by construction
    csr_w[pos] = 1.0f / (float)(c > 0 ? c : 1);
}

// ---------------------------------------------------------------------------
// Pack [root ; W_0..7] (fp32, Wcat is [1152][FOUT]) into B-fragment layout bf16:
// Wpack[ct][ks][lane][j] = Wcat[ks*32 + (lane>>4)*8 + j][ct*16 + (lane&15)]
// ---------------------------------------------------------------------------
__global__ void pack_kernel(const float* __restrict__ root, const float* __restrict__ W,
                            unsigned short* __restrict__ Wpack, int FOUT) {
    int NCT = FOUT / 16;
    int total = NCT * KSTEPS * 64;
    int idx = blockIdx.x * blockDim.x + threadIdx.x;
    if (idx >= total) return;
    int lane = idx & 63;
    int ks = (idx >> 6) % KSTEPS;
    int ct = idx / (KSTEPS * 64);
    int kbase = ks * 32 + (lane >> 4) * 8;
    int col = ct * 16 + (lane & 15);
    union { unsigned short us[8]; uint4 v; } u;
#pragma unroll
    for (int j = 0; j < 8; j++) {
        int k = kbase + j;
        float val = (k < 128) ? root[(size_t)k * FOUT + col]
                              : W[(size_t)(k - 128) * FOUT + col];
        u.us[j] = f2bf(val);
    }
    ((uint4*)Wpack)[idx] = u.v;
}

// ---------------------------------------------------------------------------
// Fused layer: per 16-node tile, gather-aggregate 8 relations into LDS (bf16)
// then GEMM [16 x 1152] @ [1152 x FOUT] with mfma_f32_16x16x32_bf16.
// ---------------------------------------------------------------------------
template <int FOUT, bool RELU>
__global__ __launch_bounds__(256) void layer_kernel(
    const float* __restrict__ X,            // [N][128] fp32
    const int* __restrict__ rowstart,
    const int* __restrict__ csr_st,
    const float* __restrict__ csr_w,
    const unsigned short* __restrict__ Wpack,  // [NCT][36][64][8] bf16 bits
    const float* __restrict__ bias,            // [FOUT]
    float* __restrict__ Y)                     // [N][FOUT]
{
    constexpr int NCT = FOUT / 16;
    __shared__ unsigned short Abuf[16][A_STRIDE];
    __shared__ float red[(NCT == 1) ? 4 : 1][64][4];

    int tid = threadIdx.x;
    int wave = tid >> 6, lane = tid & 63;
    int node0 = blockIdx.x * 16;

    // ---------------- Phase A: aggregation (wave per node, lane = 2 features)
    {
        int fo = 2 * lane;
        for (int i = 0; i < 4; i++) {
            int n = wave * 4 + i;
            int gn = node0 + n;
            float2 acc[8];
#pragma unroll
            for (int r = 0; r < 8; r++) { acc[r].x = 0.f; acc[r].y = 0.f; }
            float2 self = *(const float2*)(X + (size_t)gn * 128 + fo);
            int e0 = rowstart[gn], e1 = rowstart[gn + 1];
            for (int e = e0; e < e1; e++) {
                int st = csr_st[e];
                float wgt = csr_w[e];
                float2 xv = *(const float2*)(X + (size_t)(st & 0xFFFFFF) * 128 + fo);
                switch (st >> 24) {
                    case 0: acc[0].x += wgt * xv.x; acc[0].y += wgt * xv.y; break;
                    case 1: acc[1].x += wgt * xv.x; acc[1].y += wgt * xv.y; break;
                    case 2: acc[2].x += wgt * xv.x; acc[2].y += wgt * xv.y; break;
                    case 3: acc[3].x += wgt * xv.x; acc[3].y += wgt * xv.y; break;
                    case 4: acc[4].x += wgt * xv.x; acc[4].y += wgt * xv.y; break;
                    case 5: acc[5].x += wgt * xv.x; acc[5].y += wgt * xv.y; break;
                    case 6: acc[6].x += wgt * xv.x; acc[6].y += wgt * xv.y; break;
                    default: acc[7].x += wgt * xv.x; acc[7].y += wgt * xv.y; break;
                }
            }
            unsigned short* row = &Abuf[n][0];
            unsigned int pk = (unsigned int)f2bf(self.x) | ((unsigned int)f2bf(self.y) << 16);
            *(unsigned int*)&row[fo] = pk;
#pragma unroll
            for (int r = 0; r < 8; r++) {
                unsigned int p = (unsigned int)f2bf(acc[r].x) | ((unsigned int)f2bf(acc[r].y) << 16);
                *(unsigned int*)&row[(1 + r) * 128 + fo] = p;
            }
        }
    }
    __syncthreads();

    // ---------------- Phase B: MFMA GEMM
    int quad = lane >> 4, l16 = lane & 15;
    if constexpr (NCT >= 4) {
        constexpr int CPW = NCT / 4;   // col-tiles per wave (2 for FOUT=128)
        f32x4 acc[CPW];
#pragma unroll
        for (int c = 0; c < CPW; c++) acc[c] = (f32x4){0.f, 0.f, 0.f, 0.f};
        for (int ks = 0; ks < KSTEPS; ks++) {
            short8 a = *(const short8*)&Abuf[l16][ks * 32 + quad * 8];
#pragma unroll
            for (int c = 0; c < CPW; c++) {
                int ct = wave * CPW + c;
                short8 b = *(const short8*)(Wpack + (((size_t)ct * KSTEPS + ks) * 64 + lane) * 8);
                acc[c] = __builtin_amdgcn_mfma_f32_16x16x32_bf16(a, b, acc[c], 0, 0, 0);
            }
        }
#pragma unroll
        for (int c = 0; c < CPW; c++) {
            int ct = wave * CPW + c;
            int h = ct * 16 + l16;
            float bv = bias[h];
#pragma unroll
            for (int r = 0; r < 4; r++) {
                int node = node0 + quad * 4 + r;
                float v = acc[c][r] + bv;
                if (RELU) v = v > 0.f ? v : 0.f;
                Y[(size_t)node * FOUT + h] = v;
            }
        }
    } else {
        // FOUT=16: single col-tile, 4-way K-split across waves + LDS reduce
        f32x4 acc = (f32x4){0.f, 0.f, 0.f, 0.f};
        for (int ks = wave * 9; ks < wave * 9 + 9; ks++) {
            short8 a = *(const short8*)&Abuf[l16][ks * 32 + quad * 8];
            short8 b = *(const short8*)(Wpack + (((size_t)ks) * 64 + lane) * 8);
            acc = __builtin_amdgcn_mfma_f32_16x16x32_bf16(a, b, acc, 0, 0, 0);
        }
#pragma unroll
        for (int r = 0; r < 4; r++) red[wave][lane][r] = acc[r];
        __syncthreads();
        {
            int l = tid & 63, reg = tid >> 6;
            float s = red[0][l][reg] + red[1][l][reg] + red[2][l][reg] + red[3][l][reg];
            int node = node0 + ((l >> 4) << 2) + reg;
            int h = l & 15;
            float v = s + bias[h];
            if (RELU) v = v > 0.f ? v : 0.f;
            Y[(size_t)node * FOUT + h] = v;
        }
    }
}

// ---------------------------------------------------------------------------
extern "C" void kernel_launch(void* const* d_in, const int* in_sizes, int n_in,
                              void* d_out, int out_size, void* d_ws, size_t ws_size,
                              hipStream_t stream) {
    const float* x  = (const float*)d_in[0];
    const int*   ei = (const int*)d_in[1];
    const int*   et = (const int*)d_in[2];
    const float* w0 = (const float*)d_in[3];
    const float* r0 = (const float*)d_in[4];
    const float* b0 = (const float*)d_in[5];
    const float* w1 = (const float*)d_in[6];
    const float* r1 = (const float*)d_in[7];
    const float* b1 = (const float*)d_in[8];
    const float* w2 = (const float*)d_in[9];
    const float* r2 = (const float*)d_in[10];
    const float* b2 = (const float*)d_in[11];

    char* wsp = (char*)d_ws;
    size_t off = 0;
    auto alloc = [&](size_t bytes) -> void* {
        void* p = wsp + off;
        off += (bytes + 255) & ~(size_t)255;
        return p;
    };

    int* deg = (int*)alloc((size_t)N_NODES * 36);         // deg[N] + cnt[N*8] contiguous
    int* cnt = deg + N_NODES;
    int* rowstart = (int*)alloc(((size_t)N_NODES + 1) * 4);
    int* cursor   = (int*)alloc((size_t)N_NODES * 4);
    int* csr_st   = (int*)alloc((size_t)N_EDGES * 4);
    float* csr_w  = (float*)alloc((size_t)N_EDGES * 4);
    unsigned short* Wp0 = (unsigned short*)alloc((size_t)8 * KSTEPS * 64 * 8 * 2);
    unsigned short* Wp1 = (unsigned short*)alloc((size_t)8 * KSTEPS * 64 * 8 * 2);
    unsigned short* Wp2 = (unsigned short*)alloc((size_t)1 * KSTEPS * 64 * 8 * 2);
    float* h0 = (float*)alloc((size_t)N_NODES * 128 * 4);
    float* h1 = (float*)alloc((size_t)N_NODES * 128 * 4);

    hipMemsetAsync(deg, 0, (size_t)N_NODES * 36, stream);

    count_kernel<<<dim3((N_EDGES + 255) / 256), dim3(256), 0, stream>>>(ei, et, deg, cnt, N_EDGES);
    scan_kernel<<<dim3(1), dim3(1024), 0, stream>>>(deg, rowstart, cursor, N_NODES, N_EDGES);
    scatter_kernel<<<dim3((N_EDGES + 255) / 256), dim3(256), 0, stream>>>(ei, et, cnt, cursor,
                                                                          csr_st, csr_w, N_EDGES);
    pack_kernel<<<dim3((8 * KSTEPS * 64 + 255) / 256), dim3(256), 0, stream>>>(r0, w0, Wp0, 128);
    pack_kernel<<<dim3((8 * KSTEPS * 64 + 255) / 256), dim3(256), 0, stream>>>(r1, w1, Wp1, 128);
    pack_kernel<<<dim3((1 * KSTEPS * 64 + 255) / 256), dim3(256), 0, stream>>>(r2, w2, Wp2, 16);

    layer_kernel<128, true ><<<dim3(N_NODES / 16), dim3(256), 0, stream>>>(
        x, rowstart, csr_st, csr_w, Wp0, b0, h0);
    layer_kernel<128, true ><<<dim3(N_NODES / 16), dim3(256), 0, stream>>>(
        h0, rowstart, csr_st, csr_w, Wp1, b1, h1);
    layer_kernel<16, false><<<dim3(N_NODES / 16), dim3(256), 0, stream>>>(
        h1, rowstart, csr_st, csr_w, Wp2, b2, (float*)d_out);
}

// Round 2
// 698.292 us; speedup vs baseline: 1.3160x; 1.3160x over previous
//
#include <hip/hip_runtime.h>

#define N_NODES 50000
#define N_EDGES 800000
#define NREL 8
#define KSTEPS 36            // 1152 / 32
#define A_STRIDE 1160        // shorts per LDS row: 2320 B, multiple of 16 B

typedef __attribute__((ext_vector_type(8))) short short8;
typedef __attribute__((ext_vector_type(4))) float f32x4;

__device__ __forceinline__ unsigned short f2bf(float v) {
    union { float f; unsigned int u; } c; c.f = v;
    return (unsigned short)((c.u + 0x7FFFu + ((c.u >> 16) & 1u)) >> 16);
}
__device__ __forceinline__ float bfhi2f(unsigned int u) {   // high 16 bits as fp32
    union { unsigned int u; float f; } c; c.u = u & 0xFFFF0000u; return c.f;
}
__device__ __forceinline__ float bflo2f(unsigned int u) {   // low 16 bits as fp32
    union { unsigned int u; float f; } c; c.u = u << 16; return c.f;
}

// ---------------------------------------------------------------------------
// CSR construction: cnt per (node, rel) -> chunked scan -> scatter
// ---------------------------------------------------------------------------
__global__ void count_kernel(const int* __restrict__ ei, const int* __restrict__ et,
                             int* __restrict__ cnt, int E) {
    int e = blockIdx.x * blockDim.x + threadIdx.x;
    if (e >= E) return;
    int d = ei[E + e];
    int t = et[e];
    atomicAdd(&cnt[d * NREL + t], 1);
}

__global__ void scan_kernel(const int* __restrict__ cnt, int* __restrict__ rowstart,
                            int* __restrict__ cursor, int N, int E) {
    __shared__ int part[1024];
    int t = threadIdx.x;
    const int chunk = (N + 1023) / 1024;            // 49
    int n0 = t * chunk, n1 = n0 + chunk; if (n1 > N) n1 = N;
    int s = 0;
    for (int n = n0; n < n1; n++) {
        const int4* c4 = (const int4*)(cnt + (size_t)n * 8);
        int4 a = c4[0], b = c4[1];
        int d = a.x + a.y + a.z + a.w + b.x + b.y + b.z + b.w;
        rowstart[n] = d;                             // temp: store degree
        s += d;
    }
    part[t] = s;
    __syncthreads();
    for (int off = 1; off < 1024; off <<= 1) {
        int v = (t >= off) ? part[t - off] : 0;
        __syncthreads();
        part[t] += v;
        __syncthreads();
    }
    int run = (t > 0) ? part[t - 1] : 0;
    for (int n = n0; n < n1; n++) {
        int d = rowstart[n];
        rowstart[n] = run; cursor[n] = run; run += d;
    }
    if (t == 1023) rowstart[N] = E;
}

__global__ void scatter_kernel(const int* __restrict__ ei, const int* __restrict__ et,
                               int* __restrict__ cursor, int* __restrict__ csr_meta, int E) {
    int e = blockIdx.x * blockDim.x + threadIdx.x;
    if (e >= E) return;
    int s = ei[e];              // src < 65536 (N = 50000)
    int d = ei[E + e];
    int t = et[e];
    int pos = atomicAdd(&cursor[d], 1);
    csr_meta[pos] = (s & 0xFFFF) | (t << 16);
}

// ---------------------------------------------------------------------------
// fp32 -> bf16 conversion of X (once)
// ---------------------------------------------------------------------------
__global__ void xcast_kernel(const float* __restrict__ X, unsigned int* __restrict__ Xb2, int n4) {
    int i = blockIdx.x * blockDim.x + threadIdx.x;
    if (i >= n4) return;
    float4 v = ((const float4*)X)[i];
    unsigned int p0 = (unsigned int)f2bf(v.x) | ((unsigned int)f2bf(v.y) << 16);
    unsigned int p1 = (unsigned int)f2bf(v.z) | ((unsigned int)f2bf(v.w) << 16);
    ((uint2*)Xb2)[i] = make_uint2(p0, p1);
}

// ---------------------------------------------------------------------------
// Pack [root ; W_0..7] into B-fragment layout bf16:
// Wpack[ct][ks][lane][j] = Wcat[ks*32 + (lane>>4)*8 + j][ct*16 + (lane&15)]
// ---------------------------------------------------------------------------
__global__ void pack_kernel(const float* __restrict__ root, const float* __restrict__ W,
                            unsigned short* __restrict__ Wpack, int FOUT) {
    int NCT = FOUT / 16;
    int total = NCT * KSTEPS * 64;
    int idx = blockIdx.x * blockDim.x + threadIdx.x;
    if (idx >= total) return;
    int lane = idx & 63;
    int ks = (idx >> 6) % KSTEPS;
    int ct = idx / (KSTEPS * 64);
    int kbase = ks * 32 + (lane >> 4) * 8;
    int col = ct * 16 + (lane & 15);
    union { unsigned short us[8]; uint4 v; } u;
#pragma unroll
    for (int j = 0; j < 8; j++) {
        int k = kbase + j;
        float val = (k < 128) ? root[(size_t)k * FOUT + col]
                              : W[(size_t)(k - 128) * FOUT + col];
        u.us[j] = f2bf(val);
    }
    ((uint4*)Wpack)[idx] = u.v;
}

// ---------------------------------------------------------------------------
// Fused layer: 32 nodes/block, 8 waves. Phase A: unroll-8 gather into LDS
// (bf16 input, raw sums scaled by 1/cnt). Phase B: MFMA GEMM.
// ---------------------------------------------------------------------------
#define ACCUM_EDGE(K)                                                          \
    do {                                                                       \
        int ty = __builtin_amdgcn_readfirstlane(((unsigned)m[K]) >> 16);       \
        float f0 = bflo2f(xp[K]);                                              \
        float f1 = bfhi2f(xp[K]);                                              \
        switch (ty) {                                                          \
            case 0: acc[0].x += f0; acc[0].y += f1; break;                     \
            case 1: acc[1].x += f0; acc[1].y += f1; break;                     \
            case 2: acc[2].x += f0; acc[2].y += f1; break;                     \
            case 3: acc[3].x += f0; acc[3].y += f1; break;                     \
            case 4: acc[4].x += f0; acc[4].y += f1; break;                     \
            case 5: acc[5].x += f0; acc[5].y += f1; break;                     \
            case 6: acc[6].x += f0; acc[6].y += f1; break;                     \
            default: acc[7].x += f0; acc[7].y += f1; break;                    \
        }                                                                      \
    } while (0)

template <int FOUT, bool RELU>
__global__ __launch_bounds__(512, 4) void layer_kernel(
    const unsigned int* __restrict__ Xb2,      // [N][64] dword pairs of bf16
    const int* __restrict__ rowstart,          // [N+1]
    const int* __restrict__ csr_meta,          // [E]: src | type<<16
    const int* __restrict__ cnt,               // [N][8]
    const unsigned short* __restrict__ Wpack,  // [NCT][36][64][8]
    const float* __restrict__ bias,            // [FOUT]
    void* __restrict__ Yout)                   // bf16 [N][128] or fp32 [N][16]
{
    constexpr int NCT = FOUT / 16;
    __shared__ __align__(16) unsigned short Abuf[32][A_STRIDE];

    int tid = threadIdx.x;
    int wave = tid >> 6, lane = tid & 63;
    int node0 = blockIdx.x * 32;

    // ---------------- Phase A
    for (int i = 0; i < 4; i++) {
        int n = wave * 4 + i;
        int gn = node0 + n;
        unsigned int* row32 = (unsigned int*)&Abuf[n][0];   // 64 dwords per 128-feat segment
        if (gn >= N_NODES) {
            row32[lane] = 0;
#pragma unroll
            for (int r = 0; r < 8; r++) row32[(1 + r) * 64 + lane] = 0;
            continue;
        }
        row32[lane] = Xb2[(size_t)gn * 64 + lane];          // self row (already bf16)
        float2 acc[8];
#pragma unroll
        for (int r = 0; r < 8; r++) { acc[r].x = 0.f; acc[r].y = 0.f; }
        int e0 = __builtin_amdgcn_readfirstlane(rowstart[gn]);
        int e1 = __builtin_amdgcn_readfirstlane(rowstart[gn + 1]);
        int e = e0;
        for (; e + 8 <= e1; e += 8) {
            int m[8];
            unsigned int xp[8];
#pragma unroll
            for (int k = 0; k < 8; k++) m[k] = csr_meta[e + k];
#pragma unroll
            for (int k = 0; k < 8; k++)
                xp[k] = Xb2[(size_t)(m[k] & 0xFFFF) * 64 + lane];
            ACCUM_EDGE(0); ACCUM_EDGE(1); ACCUM_EDGE(2); ACCUM_EDGE(3);
            ACCUM_EDGE(4); ACCUM_EDGE(5); ACCUM_EDGE(6); ACCUM_EDGE(7);
        }
        for (; e < e1; e++) {
            int m[1]; unsigned int xp[1];
            m[0] = csr_meta[e];
            xp[0] = Xb2[(size_t)(m[0] & 0xFFFF) * 64 + lane];
            ACCUM_EDGE(0);
        }
        // scale by 1/max(cnt,1), convert, store
        const int4* c4 = (const int4*)(cnt + (size_t)gn * 8);
        int4 ca = c4[0], cb = c4[1];
        int cs[8] = {ca.x, ca.y, ca.z, ca.w, cb.x, cb.y, cb.z, cb.w};
#pragma unroll
        for (int r = 0; r < 8; r++) {
            float inv = 1.0f / (float)(cs[r] > 0 ? cs[r] : 1);
            unsigned int p = (unsigned int)f2bf(acc[r].x * inv)
                           | ((unsigned int)f2bf(acc[r].y * inv) << 16);
            row32[(1 + r) * 64 + lane] = p;
        }
    }
    __syncthreads();

    // ---------------- Phase B
    int quad = lane >> 4, l16 = lane & 15;
    if constexpr (NCT == 8) {
        int ct = wave;                               // 8 waves, 8 col-tiles
        f32x4 acc0 = (f32x4){0.f, 0.f, 0.f, 0.f};
        f32x4 acc1 = (f32x4){0.f, 0.f, 0.f, 0.f};
        for (int ks = 0; ks < KSTEPS; ks++) {
            short8 b = *(const short8*)(Wpack + (((size_t)ct * KSTEPS + ks) * 64 + lane) * 8);
            short8 a0 = *(const short8*)&Abuf[l16][ks * 32 + quad * 8];
            short8 a1 = *(const short8*)&Abuf[16 + l16][ks * 32 + quad * 8];
            acc0 = __builtin_amdgcn_mfma_f32_16x16x32_bf16(a0, b, acc0, 0, 0, 0);
            acc1 = __builtin_amdgcn_mfma_f32_16x16x32_bf16(a1, b, acc1, 0, 0, 0);
        }
        unsigned short* Yb = (unsigned short*)Yout;
        int h = ct * 16 + l16;
        float bv = bias[h];
#pragma unroll
        for (int rt = 0; rt < 2; rt++) {
            f32x4 a = rt ? acc1 : acc0;
#pragma unroll
            for (int r = 0; r < 4; r++) {
                int node = node0 + rt * 16 + quad * 4 + r;
                if (node < N_NODES) {
                    float v = a[r] + bv;
                    if (RELU) v = v > 0.f ? v : 0.f;
                    Yb[(size_t)node * 128 + h] = f2bf(v);
                }
            }
        }
    } else {
        // FOUT=16: waves 0-3 row-tile 0, waves 4-7 row-tile 1; K split 4 ways
        int rt = wave >> 2, kg = wave & 3;
        f32x4 acc = (f32x4){0.f, 0.f, 0.f, 0.f};
        for (int ks = kg * 9; ks < kg * 9 + 9; ks++) {
            short8 b = *(const short8*)(Wpack + (((size_t)ks) * 64 + lane) * 8);
            short8 a = *(const short8*)&Abuf[rt * 16 + l16][ks * 32 + quad * 8];
            acc = __builtin_amdgcn_mfma_f32_16x16x32_bf16(a, b, acc, 0, 0, 0);
        }
        __syncthreads();                              // all Abuf reads done -> alias red
        float* red = (float*)&Abuf[0][0];             // [2][4][64][4] = 8 KB
#pragma unroll
        for (int r = 0; r < 4; r++)
            red[(((rt * 4 + kg) * 64 + lane) << 2) + r] = acc[r];
        __syncthreads();
        {
            int rt2 = tid >> 8, reg = (tid >> 6) & 3, l = tid & 63;
            float s = red[(((rt2 * 4 + 0) * 64 + l) << 2) + reg]
                    + red[(((rt2 * 4 + 1) * 64 + l) << 2) + reg]
                    + red[(((rt2 * 4 + 2) * 64 + l) << 2) + reg]
                    + red[(((rt2 * 4 + 3) * 64 + l) << 2) + reg];
            int node = node0 + rt2 * 16 + ((l >> 4) << 2) + reg;
            int h = l & 15;
            if (node < N_NODES) {
                float v = s + bias[h];
                if (RELU) v = v > 0.f ? v : 0.f;
                ((float*)Yout)[(size_t)node * 16 + h] = v;
            }
        }
    }
}

// ---------------------------------------------------------------------------
extern "C" void kernel_launch(void* const* d_in, const int* in_sizes, int n_in,
                              void* d_out, int out_size, void* d_ws, size_t ws_size,
                              hipStream_t stream) {
    const float* x  = (const float*)d_in[0];
    const int*   ei = (const int*)d_in[1];
    const int*   et = (const int*)d_in[2];
    const float* w0 = (const float*)d_in[3];
    const float* r0 = (const float*)d_in[4];
    const float* b0 = (const float*)d_in[5];
    const float* w1 = (const float*)d_in[6];
    const float* r1 = (const float*)d_in[7];
    const float* b1 = (const float*)d_in[8];
    const float* w2 = (const float*)d_in[9];
    const float* r2 = (const float*)d_in[10];
    const float* b2 = (const float*)d_in[11];

    char* wsp = (char*)d_ws;
    size_t off = 0;
    auto alloc = [&](size_t bytes) -> void* {
        void* p = wsp + off;
        off += (bytes + 255) & ~(size_t)255;
        return p;
    };

    int* cnt      = (int*)alloc((size_t)N_NODES * 8 * 4);
    int* rowstart = (int*)alloc(((size_t)N_NODES + 1) * 4);
    int* cursor   = (int*)alloc((size_t)N_NODES * 4);
    int* csr_meta = (int*)alloc((size_t)N_EDGES * 4);
    unsigned short* Wp0 = (unsigned short*)alloc((size_t)8 * KSTEPS * 64 * 8 * 2);
    unsigned short* Wp1 = (unsigned short*)alloc((size_t)8 * KSTEPS * 64 * 8 * 2);
    unsigned short* Wp2 = (unsigned short*)alloc((size_t)1 * KSTEPS * 64 * 8 * 2);
    unsigned int* Xb = (unsigned int*)alloc((size_t)N_NODES * 64 * 4);
    unsigned int* H0 = (unsigned int*)alloc((size_t)N_NODES * 64 * 4);
    unsigned int* H1 = (unsigned int*)alloc((size_t)N_NODES * 64 * 4);

    hipMemsetAsync(cnt, 0, (size_t)N_NODES * 8 * 4, stream);

    count_kernel<<<dim3((N_EDGES + 255) / 256), dim3(256), 0, stream>>>(ei, et, cnt, N_EDGES);
    scan_kernel<<<dim3(1), dim3(1024), 0, stream>>>(cnt, rowstart, cursor, N_NODES, N_EDGES);
    scatter_kernel<<<dim3((N_EDGES + 255) / 256), dim3(256), 0, stream>>>(ei, et, cursor,
                                                                          csr_meta, N_EDGES);
    xcast_kernel<<<dim3((N_NODES * 32 + 255) / 256), dim3(256), 0, stream>>>(
        x, Xb, N_NODES * 32);
    pack_kernel<<<dim3((8 * KSTEPS * 64 + 255) / 256), dim3(256), 0, stream>>>(r0, w0, Wp0, 128);
    pack_kernel<<<dim3((8 * KSTEPS * 64 + 255) / 256), dim3(256), 0, stream>>>(r1, w1, Wp1, 128);
    pack_kernel<<<dim3((1 * KSTEPS * 64 + 255) / 256), dim3(256), 0, stream>>>(r2, w2, Wp2, 16);

    int nblk = (N_NODES + 31) / 32;
    layer_kernel<128, true ><<<dim3(nblk), dim3(512), 0, stream>>>(
        Xb, rowstart, csr_meta, cnt, Wp0, b0, (void*)H0);
    layer_kernel<128, true ><<<dim3(nblk), dim3(512), 0, stream>>>(
        H0, rowstart, csr_meta, cnt, Wp1, b1, (void*)H1);
    layer_kernel<16, false><<<dim3(nblk), dim3(512), 0, stream>>>(
        H1, rowstart, csr_meta, cnt, Wp2, b2, d_out);
}

// Round 3
// 392.330 us; speedup vs baseline: 2.3423x; 1.7799x over previous
//
#include <hip/hip_runtime.h>

#define N_NODES 50000
#define N_EDGES 800000
#define NREL 8
#define NB8 (N_NODES * NREL)      // 400000
#define SCAN_T 12500              // NB8 / 32
#define KSTEPS 36                 // 1152 / 32
#define A_STRIDE 1160             // shorts per LDS row: 580 dwords, %32 == 4

typedef __attribute__((ext_vector_type(8))) short short8;
typedef __attribute__((ext_vector_type(4))) float f32x4;

__device__ __forceinline__ unsigned short f2bf(float v) {
    union { float f; unsigned int u; } c; c.f = v;
    return (unsigned short)((c.u + 0x7FFFu + ((c.u >> 16) & 1u)) >> 16);
}
__device__ __forceinline__ float bfhi2f(unsigned int u) {
    union { unsigned int u; float f; } c; c.u = u & 0xFFFF0000u; return c.f;
}
__device__ __forceinline__ float bflo2f(unsigned int u) {
    union { unsigned int u; float f; } c; c.u = u << 16; return c.f;
}

// ---------------------------------------------------------------------------
// CSR build: count per (dst, rel) -> 3-stage scan -> scatter sorted by (dst,rel)
// ---------------------------------------------------------------------------
__global__ void count_kernel(const int* __restrict__ ei, const int* __restrict__ et,
                             int* __restrict__ cnt, int E) {
    int e = blockIdx.x * blockDim.x + threadIdx.x;
    if (e >= E) return;
    int d = ei[E + e];
    int t = et[e];
    atomicAdd(&cnt[d * NREL + t], 1);
}

__global__ void scanA_kernel(const int* __restrict__ cnt, int* __restrict__ tsum) {
    int g = blockIdx.x * blockDim.x + threadIdx.x;
    if (g >= SCAN_T) return;
    const int4* p = (const int4*)(cnt + (size_t)g * 32);
    int s = 0;
#pragma unroll
    for (int j = 0; j < 8; j++) {
        int4 v = p[j];
        s += v.x + v.y + v.z + v.w;
    }
    tsum[g] = s;
}

__global__ void scanB_kernel(const int* __restrict__ tsum, int* __restrict__ toff) {
    __shared__ int part[1024];
    int t = threadIdx.x;
    const int C = 13;                       // 1024*13 >= 12500
    int n0 = t * C, n1 = n0 + C; if (n1 > SCAN_T) n1 = SCAN_T;
    int s = 0;
    for (int n = n0; n < n1; n++) s += tsum[n];
    part[t] = s;
    __syncthreads();
    for (int off = 1; off < 1024; off <<= 1) {
        int v = (t >= off) ? part[t - off] : 0;
        __syncthreads();
        part[t] += v;
        __syncthreads();
    }
    int run = (t > 0) ? part[t - 1] : 0;
    for (int n = n0; n < n1; n++) { toff[n] = run; run += tsum[n]; }
}

__global__ void scanC_kernel(const int* __restrict__ cnt, const int* __restrict__ toff,
                             int* __restrict__ rs8, int* __restrict__ cursor) {
    int g = blockIdx.x * blockDim.x + threadIdx.x;
    if (g >= SCAN_T) return;
    int run = toff[g];
    int base = g * 32;
#pragma unroll 4
    for (int j = 0; j < 32; j++) {
        rs8[base + j] = run;
        cursor[base + j] = run;
        run += cnt[base + j];
    }
    if (g == 0) rs8[NB8] = N_EDGES;
}

__global__ void scatter_kernel(const int* __restrict__ ei, const int* __restrict__ et,
                               int* __restrict__ cursor, unsigned short* __restrict__ csr_src,
                               int E) {
    int e = blockIdx.x * blockDim.x + threadIdx.x;
    if (e >= E) return;
    int s = ei[e];                 // < 50000, fits 16 bits
    int d = ei[E + e];
    int t = et[e];
    int pos = atomicAdd(&cursor[d * NREL + t], 1);
    csr_src[pos] = (unsigned short)s;
}

// ---------------------------------------------------------------------------
// fp32 -> bf16 cast of X
// ---------------------------------------------------------------------------
__global__ void xcast_kernel(const float* __restrict__ X, unsigned int* __restrict__ Xb2, int n4) {
    int i = blockIdx.x * blockDim.x + threadIdx.x;
    if (i >= n4) return;
    float4 v = ((const float4*)X)[i];
    unsigned int p0 = (unsigned int)f2bf(v.x) | ((unsigned int)f2bf(v.y) << 16);
    unsigned int p1 = (unsigned int)f2bf(v.z) | ((unsigned int)f2bf(v.w) << 16);
    ((uint2*)Xb2)[i] = make_uint2(p0, p1);
}

// ---------------------------------------------------------------------------
// Pack [root ; W_0..7] into B-fragment layout bf16:
// Wpack[ct][ks][lane][j] = Wcat[ks*32 + (lane>>4)*8 + j][ct*16 + (lane&15)]
// ---------------------------------------------------------------------------
__global__ void pack_kernel(const float* __restrict__ root, const float* __restrict__ W,
                            unsigned short* __restrict__ Wpack, int FOUT) {
    int NCT = FOUT / 16;
    int total = NCT * KSTEPS * 64;
    int idx = blockIdx.x * blockDim.x + threadIdx.x;
    if (idx >= total) return;
    int lane = idx & 63;
    int ks = (idx >> 6) % KSTEPS;
    int ct = idx / (KSTEPS * 64);
    int kbase = ks * 32 + (lane >> 4) * 8;
    int col = ct * 16 + (lane & 15);
    union { unsigned short us[8]; uint4 v; } u;
#pragma unroll
    for (int j = 0; j < 8; j++) {
        int k = kbase + j;
        float val = (k < 128) ? root[(size_t)k * FOUT + col]
                              : W[(size_t)(k - 128) * FOUT + col];
        u.us[j] = f2bf(val);
    }
    ((uint4*)Wpack)[idx] = u.v;
}

// ---------------------------------------------------------------------------
// Fused layer: 16 nodes/block, 512 threads, 4 blocks/CU.
// Phase A: 2 nodes/wave; edges sorted by (dst,rel) -> single accumulator with
// scalar segment-boundary flush; meta prefetched one batch ahead.
// Phase B: MFMA GEMM [16 x 1152] @ [1152 x FOUT].
// ---------------------------------------------------------------------------
template <int FOUT, bool RELU>
__global__ __launch_bounds__(512, 8) void layer_kernel(
    const unsigned int* __restrict__ Xb2,        // [N][64] bf16 dword pairs
    const int* __restrict__ rs8,                 // [NB8+1] segment starts
    const unsigned short* __restrict__ csr_src,  // [E] src ids, sorted by (dst,rel)
    const unsigned short* __restrict__ Wpack,    // [NCT][36][64][8]
    const float* __restrict__ bias,
    void* __restrict__ Yout)                     // bf16 [N][128] or fp32 [N][16]
{
    __shared__ __align__(16) unsigned short Abuf[16][A_STRIDE];

    int tid = threadIdx.x;
    int wave = tid >> 6, lane = tid & 63;
    int node0 = blockIdx.x * 16;

    // ---------------- Phase A
    for (int i = 0; i < 2; i++) {
        int n = wave * 2 + i;
        int gn = node0 + n;                            // N divisible by 16: no tail
        unsigned int* row32 = (unsigned int*)&Abuf[n][0];
        row32[lane] = Xb2[(size_t)gn * 64 + lane];     // self row

        int bl = lane <= 8 ? lane : 8;
        int bv = rs8[gn * 8 + bl];                     // lanes 0..8 hold bounds b[0..8]
        int e  = __builtin_amdgcn_readlane(bv, 0);
        int e1 = __builtin_amdgcn_readlane(bv, 8);
        int r = 0;
        int segs = e;
        int be = __builtin_amdgcn_readlane(bv, 1);
        float ax = 0.f, ay = 0.f;

#define FLUSH_R()                                                              \
        do {                                                                   \
            int c_ = be - segs;                                                \
            float iv_ = 1.0f / (float)(c_ > 0 ? c_ : 1);                       \
            unsigned int pk_ = (unsigned int)f2bf(ax * iv_)                    \
                             | ((unsigned int)f2bf(ay * iv_) << 16);           \
            row32[(1 + r) * 64 + lane] = pk_;                                  \
            ax = 0.f; ay = 0.f; segs = be; r++;                                \
            be = __builtin_amdgcn_readlane(bv, r + 1 <= 8 ? r + 1 : 8);        \
        } while (0)

        if (e < e1) {
            int e1m = e1 - 1;
            unsigned int ml[8];
#pragma unroll
            for (int k = 0; k < 8; k++) {
                int ee = e + k;
                ml[k] = csr_src[ee <= e1m ? ee : e1m];
            }
            while (e < e1) {
                int bn = e1 - e; if (bn > 8) bn = 8;
                int sc[8];
#pragma unroll
                for (int k = 0; k < 8; k++) sc[k] = __builtin_amdgcn_readfirstlane((int)ml[k]);
                unsigned int xp[8];
#pragma unroll
                for (int k = 0; k < 8; k++) xp[k] = Xb2[(size_t)sc[k] * 64 + lane];
                int en = e + bn;
                if (en < e1) {                          // prefetch next batch metas
#pragma unroll
                    for (int k = 0; k < 8; k++) {
                        int ee = en + k;
                        ml[k] = csr_src[ee <= e1m ? ee : e1m];
                    }
                }
#pragma unroll
                for (int k = 0; k < 8; k++) {
                    if (k < bn) {                       // scalar-uniform
                        int ec = e + k;
                        while (ec >= be) FLUSH_R();
                        ax += bflo2f(xp[k]);
                        ay += bfhi2f(xp[k]);
                    }
                }
                e = en;
            }
        }
        while (r < 8) FLUSH_R();
#undef FLUSH_R
    }
    __syncthreads();

    // ---------------- Phase B
    int quad = lane >> 4, l16 = lane & 15;
    if constexpr (FOUT == 128) {
        int ct = wave;                                  // 8 waves = 8 col-tiles
        f32x4 acc = (f32x4){0.f, 0.f, 0.f, 0.f};
        for (int ks = 0; ks < KSTEPS; ks++) {
            short8 b = *(const short8*)(Wpack + (((size_t)ct * KSTEPS + ks) * 64 + lane) * 8);
            short8 a = *(const short8*)&Abuf[l16][ks * 32 + quad * 8];
            acc = __builtin_amdgcn_mfma_f32_16x16x32_bf16(a, b, acc, 0, 0, 0);
        }
        unsigned short* Yb = (unsigned short*)Yout;
        int h = ct * 16 + l16;
        float bvs = bias[h];
#pragma unroll
        for (int r4 = 0; r4 < 4; r4++) {
            int node = node0 + quad * 4 + r4;
            float v = acc[r4] + bvs;
            if (RELU) v = v > 0.f ? v : 0.f;
            Yb[(size_t)node * 128 + h] = f2bf(v);
        }
    } else {
        // FOUT == 16: 8-way K-split + LDS reduce
        int ks0 = wave * 4 + (wave < 4 ? wave : 4);
        int ksn = (wave < 4) ? 5 : 4;
        f32x4 acc = (f32x4){0.f, 0.f, 0.f, 0.f};
        for (int ks = ks0; ks < ks0 + ksn; ks++) {
            short8 b = *(const short8*)(Wpack + ((size_t)ks * 64 + lane) * 8);
            short8 a = *(const short8*)&Abuf[l16][ks * 32 + quad * 8];
            acc = __builtin_amdgcn_mfma_f32_16x16x32_bf16(a, b, acc, 0, 0, 0);
        }
        __syncthreads();                                // Abuf reads done -> alias red
        float* red = (float*)&Abuf[0][0];               // [8][64][4] = 8 KB
#pragma unroll
        for (int r4 = 0; r4 < 4; r4++) red[(wave * 64 + lane) * 4 + r4] = acc[r4];
        __syncthreads();
        if (tid < 256) {
            int reg = tid >> 6, l = tid & 63;
            float s = 0.f;
#pragma unroll
            for (int w = 0; w < 8; w++) s += red[(w * 64 + l) * 4 + reg];
            int node = node0 + ((l >> 4) << 2) + reg;
            int h = l & 15;
            float v = s + bias[h];
            if (RELU) v = v > 0.f ? v : 0.f;
            ((float*)Yout)[(size_t)node * 16 + h] = v;
        }
    }
}

// ---------------------------------------------------------------------------
extern "C" void kernel_launch(void* const* d_in, const int* in_sizes, int n_in,
                              void* d_out, int out_size, void* d_ws, size_t ws_size,
                              hipStream_t stream) {
    const float* x  = (const float*)d_in[0];
    const int*   ei = (const int*)d_in[1];
    const int*   et = (const int*)d_in[2];
    const float* w0 = (const float*)d_in[3];
    const float* r0 = (const float*)d_in[4];
    const float* b0 = (const float*)d_in[5];
    const float* w1 = (const float*)d_in[6];
    const float* r1 = (const float*)d_in[7];
    const float* b1 = (const float*)d_in[8];
    const float* w2 = (const float*)d_in[9];
    const float* r2 = (const float*)d_in[10];
    const float* b2 = (const float*)d_in[11];

    char* wsp = (char*)d_ws;
    size_t off = 0;
    auto alloc = [&](size_t bytes) -> void* {
        void* p = wsp + off;
        off += (bytes + 255) & ~(size_t)255;
        return p;
    };

    int* cnt    = (int*)alloc((size_t)NB8 * 4);
    int* rs8    = (int*)alloc(((size_t)NB8 + 1) * 4);
    int* cursor = (int*)alloc((size_t)NB8 * 4);
    int* tsum   = (int*)alloc((size_t)SCAN_T * 4);
    int* toff   = (int*)alloc((size_t)SCAN_T * 4);
    unsigned short* csr_src = (unsigned short*)alloc((size_t)N_EDGES * 2);
    unsigned short* Wp0 = (unsigned short*)alloc((size_t)8 * KSTEPS * 64 * 8 * 2);
    unsigned short* Wp1 = (unsigned short*)alloc((size_t)8 * KSTEPS * 64 * 8 * 2);
    unsigned short* Wp2 = (unsigned short*)alloc((size_t)1 * KSTEPS * 64 * 8 * 2);
    unsigned int* Xb = (unsigned int*)alloc((size_t)N_NODES * 64 * 4);
    unsigned int* H0 = (unsigned int*)alloc((size_t)N_NODES * 64 * 4);
    unsigned int* H1 = (unsigned int*)alloc((size_t)N_NODES * 64 * 4);

    hipMemsetAsync(cnt, 0, (size_t)NB8 * 4, stream);

    count_kernel<<<dim3((N_EDGES + 255) / 256), dim3(256), 0, stream>>>(ei, et, cnt, N_EDGES);
    scanA_kernel<<<dim3((SCAN_T + 255) / 256), dim3(256), 0, stream>>>(cnt, tsum);
    scanB_kernel<<<dim3(1), dim3(1024), 0, stream>>>(tsum, toff);
    scanC_kernel<<<dim3((SCAN_T + 255) / 256), dim3(256), 0, stream>>>(cnt, toff, rs8, cursor);
    scatter_kernel<<<dim3((N_EDGES + 255) / 256), dim3(256), 0, stream>>>(ei, et, cursor,
                                                                          csr_src, N_EDGES);
    xcast_kernel<<<dim3((N_NODES * 32 + 255) / 256), dim3(256), 0, stream>>>(x, Xb, N_NODES * 32);
    pack_kernel<<<dim3((8 * KSTEPS * 64 + 255) / 256), dim3(256), 0, stream>>>(r0, w0, Wp0, 128);
    pack_kernel<<<dim3((8 * KSTEPS * 64 + 255) / 256), dim3(256), 0, stream>>>(r1, w1, Wp1, 128);
    pack_kernel<<<dim3((1 * KSTEPS * 64 + 255) / 256), dim3(256), 0, stream>>>(r2, w2, Wp2, 16);

    int nblk = N_NODES / 16;   // 3125, exact
    layer_kernel<128, true ><<<dim3(nblk), dim3(512), 0, stream>>>(
        Xb, rs8, csr_src, Wp0, b0, (void*)H0);
    layer_kernel<128, true ><<<dim3(nblk), dim3(512), 0, stream>>>(
        H0, rs8, csr_src, Wp1, b1, (void*)H1);
    layer_kernel<16, false><<<dim3(nblk), dim3(512), 0, stream>>>(
        H1, rs8, csr_src, Wp2, b2, d_out);
}

// Round 4
// 372.940 us; speedup vs baseline: 2.4641x; 1.0520x over previous
//
#include <hip/hip_runtime.h>

#define N_NODES 50000
#define N_EDGES 800000
#define NREL 8
#define NB8 (N_NODES * NREL)      // 400000
#define SCAN_T 12500              // NB8 / 32
#define KSTEPS 36                 // 1152 / 32
#define A_STRIDE 1160             // shorts per LDS row

typedef __attribute__((ext_vector_type(8))) short short8;
typedef __attribute__((ext_vector_type(4))) float f32x4;
typedef __attribute__((ext_vector_type(2))) float f32x2;

__device__ __forceinline__ unsigned short f2bf(float v) {
    union { float f; unsigned int u; } c; c.f = v;
    return (unsigned short)((c.u + 0x7FFFu + ((c.u >> 16) & 1u)) >> 16);
}
__device__ __forceinline__ float bfhi2f(unsigned int u) {
    union { unsigned int u; float f; } c; c.u = u & 0xFFFF0000u; return c.f;
}
__device__ __forceinline__ float bflo2f(unsigned int u) {
    union { unsigned int u; float f; } c; c.u = u << 16; return c.f;
}

// ---------------------------------------------------------------------------
// Fused prep: zero cnt + cast X to bf16 + pack 3 weight sets
// ---------------------------------------------------------------------------
#define PREP_Z   (NB8 / 4)            // 100000 int4 zero stores
#define PREP_X   (N_NODES * 32)       // 1600000 float4 casts
#define PREP_P   (8 * KSTEPS * 64)    // 18432 per 128-out pack
#define PREP_P2  (1 * KSTEPS * 64)    // 2304
#define PREP_TOTAL (PREP_Z + PREP_X + 2 * PREP_P + PREP_P2)

__device__ __forceinline__ void pack_one(int idx, const float* __restrict__ root,
                                         const float* __restrict__ W,
                                         unsigned short* __restrict__ Wpack, int FOUT) {
    int lane = idx & 63;
    int ks = (idx >> 6) % KSTEPS;
    int ct = idx / (KSTEPS * 64);
    int kbase = ks * 32 + (lane >> 4) * 8;
    int col = ct * 16 + (lane & 15);
    union { unsigned short us[8]; uint4 v; } u;
#pragma unroll
    for (int j = 0; j < 8; j++) {
        int k = kbase + j;
        float val = (k < 128) ? root[(size_t)k * FOUT + col]
                              : W[(size_t)(k - 128) * FOUT + col];
        u.us[j] = f2bf(val);
    }
    ((uint4*)Wpack)[idx] = u.v;
}

__global__ void prep_kernel(const float* __restrict__ X, unsigned int* __restrict__ Xb2,
                            const float* __restrict__ r0, const float* __restrict__ w0,
                            unsigned short* __restrict__ Wp0,
                            const float* __restrict__ r1, const float* __restrict__ w1,
                            unsigned short* __restrict__ Wp1,
                            const float* __restrict__ r2, const float* __restrict__ w2,
                            unsigned short* __restrict__ Wp2,
                            int* __restrict__ cnt) {
    int t = blockIdx.x * blockDim.x + threadIdx.x;
    if (t < PREP_Z) { ((int4*)cnt)[t] = make_int4(0, 0, 0, 0); return; }
    t -= PREP_Z;
    if (t < PREP_X) {
        float4 v = ((const float4*)X)[t];
        unsigned int p0 = (unsigned int)f2bf(v.x) | ((unsigned int)f2bf(v.y) << 16);
        unsigned int p1 = (unsigned int)f2bf(v.z) | ((unsigned int)f2bf(v.w) << 16);
        ((uint2*)Xb2)[t] = make_uint2(p0, p1);
        return;
    }
    t -= PREP_X;
    if (t < PREP_P) { pack_one(t, r0, w0, Wp0, 128); return; }
    t -= PREP_P;
    if (t < PREP_P) { pack_one(t, r1, w1, Wp1, 128); return; }
    t -= PREP_P;
    if (t < PREP_P2) pack_one(t, r2, w2, Wp2, 16);
}

// ---------------------------------------------------------------------------
// CSR build
// ---------------------------------------------------------------------------
__global__ void count_kernel(const int* __restrict__ ei, const int* __restrict__ et,
                             int* __restrict__ cnt, int E) {
    int e = blockIdx.x * blockDim.x + threadIdx.x;
    if (e >= E) return;
    int d = ei[E + e];
    int t = et[e];
    atomicAdd(&cnt[d * NREL + t], 1);
}

__global__ void scanA_kernel(const int* __restrict__ cnt, int* __restrict__ tsum) {
    int g = blockIdx.x * blockDim.x + threadIdx.x;
    if (g >= SCAN_T) return;
    const int4* p = (const int4*)(cnt + (size_t)g * 32);
    int s = 0;
#pragma unroll
    for (int j = 0; j < 8; j++) {
        int4 v = p[j];
        s += v.x + v.y + v.z + v.w;
    }
    tsum[g] = s;
}

__global__ void scanB_kernel(const int* __restrict__ tsum, int* __restrict__ toff) {
    __shared__ int part[1024];
    int t = threadIdx.x;
    const int C = 13;
    int n0 = t * C, n1 = n0 + C; if (n1 > SCAN_T) n1 = SCAN_T;
    int s = 0;
    for (int n = n0; n < n1; n++) s += tsum[n];
    part[t] = s;
    __syncthreads();
    for (int off = 1; off < 1024; off <<= 1) {
        int v = (t >= off) ? part[t - off] : 0;
        __syncthreads();
        part[t] += v;
        __syncthreads();
    }
    int run = (t > 0) ? part[t - 1] : 0;
    for (int n = n0; n < n1; n++) { toff[n] = run; run += tsum[n]; }
}

__global__ void scanC_kernel(const int* __restrict__ cnt, const int* __restrict__ toff,
                             int* __restrict__ rs8, int* __restrict__ cursor) {
    int g = blockIdx.x * blockDim.x + threadIdx.x;
    if (g >= SCAN_T) return;
    int run = toff[g];
    int base = g * 32;
#pragma unroll 4
    for (int j = 0; j < 32; j++) {
        rs8[base + j] = run;
        cursor[base + j] = run;
        run += cnt[base + j];
    }
    if (g == 0) rs8[NB8] = N_EDGES;
}

__global__ void scatter_kernel(const int* __restrict__ ei, const int* __restrict__ et,
                               int* __restrict__ cursor, unsigned short* __restrict__ csr_src,
                               int E) {
    int e = blockIdx.x * blockDim.x + threadIdx.x;
    if (e >= E) return;
    int s = ei[e];
    int d = ei[E + e];
    int t = et[e];
    int pos = atomicAdd(&cursor[d * NREL + t], 1);
    csr_src[pos] = (unsigned short)s;
}

// ---------------------------------------------------------------------------
// Fused layer: 16 nodes/block, 512 threads.
// Phase A: 2 nodes/wave; edges sorted by (dst,rel); 16-edge batches with
// lane-parallel meta load + readlane scalarization; packed f32x2 accumulate.
// Phase B: MFMA GEMM [16 x 1152] @ [1152 x FOUT].
// ---------------------------------------------------------------------------
template <int FOUT, bool RELU>
__global__ __launch_bounds__(512, 8) void layer_kernel(
    const unsigned int* __restrict__ Xb2,        // [N][64] bf16 dword pairs
    const int* __restrict__ rs8,                 // [NB8+1]
    const unsigned short* __restrict__ csr_src,  // [E] src ids sorted by (dst,rel)
    const unsigned short* __restrict__ Wpack,    // [NCT][36][64][8]
    const float* __restrict__ bias,
    void* __restrict__ Yout)
{
    __shared__ __align__(16) unsigned short Abuf[16][A_STRIDE];

    int tid = threadIdx.x;
    int wave = tid >> 6, lane = tid & 63;
    int l15 = lane & 15;
    int node0 = blockIdx.x * 16;

    // ---------------- Phase A
    for (int i = 0; i < 2; i++) {
        int n = wave * 2 + i;
        int gn = node0 + n;
        unsigned int* row32 = (unsigned int*)&Abuf[n][0];
        row32[lane] = Xb2[(size_t)gn * 64 + lane];     // self row

        int bl = lane <= 8 ? lane : 8;
        int bv = rs8[gn * 8 + bl];                     // lanes 0..8 hold bounds
        int e  = __builtin_amdgcn_readlane(bv, 0);
        int e1 = __builtin_amdgcn_readlane(bv, 8);
        int r = 0;
        int segs = e;
        int be = __builtin_amdgcn_readlane(bv, 1);
        f32x2 av = (f32x2){0.f, 0.f};

#define FLUSH_R()                                                              \
        do {                                                                   \
            int c_ = be - segs;                                                \
            float iv_ = 1.0f / (float)(c_ > 0 ? c_ : 1);                       \
            unsigned int pk_ = (unsigned int)f2bf(av.x * iv_)                  \
                             | ((unsigned int)f2bf(av.y * iv_) << 16);         \
            row32[(1 + r) * 64 + lane] = pk_;                                  \
            av = (f32x2){0.f, 0.f}; segs = be; r++;                            \
            be = __builtin_amdgcn_readlane(bv, r + 1 <= 8 ? r + 1 : 8);        \
        } while (0)

        if (e < e1) {
            int e1m = e1 - 1;
            int ma = e + l15; if (ma > e1m) ma = e1m;
            unsigned int mv = csr_src[ma];             // lanes 0-15: metas e..e+15
            while (e < e1) {
                int bn = e1 - e; if (bn > 16) bn = 16;
                int sc[16];
#pragma unroll
                for (int k = 0; k < 16; k++) sc[k] = __builtin_amdgcn_readlane((int)mv, k);
                unsigned int xp[16];
#pragma unroll
                for (int k = 0; k < 16; k++) xp[k] = Xb2[(size_t)sc[k] * 64 + lane];
                int en = e + bn;
                if (en < e1) {                          // prefetch next meta window
                    int mb = en + l15; if (mb > e1m) mb = e1m;
                    mv = csr_src[mb];
                }
#pragma unroll
                for (int k = 0; k < 16; k++) {
                    if (k < bn) {                       // bn is wave-uniform
                        int ec = e + k;
                        while (ec >= be) FLUSH_R();
                        av += (f32x2){bflo2f(xp[k]), bfhi2f(xp[k])};
                    }
                }
                e = en;
            }
        }
        while (r < 8) FLUSH_R();
#undef FLUSH_R
    }
    __syncthreads();

    // ---------------- Phase B
    int quad = lane >> 4, l16 = lane & 15;
    if constexpr (FOUT == 128) {
        int ct = wave;
        f32x4 acc = (f32x4){0.f, 0.f, 0.f, 0.f};
        for (int ks = 0; ks < KSTEPS; ks++) {
            short8 b = *(const short8*)(Wpack + (((size_t)ct * KSTEPS + ks) * 64 + lane) * 8);
            short8 a = *(const short8*)&Abuf[l16][ks * 32 + quad * 8];
            acc = __builtin_amdgcn_mfma_f32_16x16x32_bf16(a, b, acc, 0, 0, 0);
        }
        unsigned short* Yb = (unsigned short*)Yout;
        int h = ct * 16 + l16;
        float bvs = bias[h];
#pragma unroll
        for (int r4 = 0; r4 < 4; r4++) {
            int node = node0 + quad * 4 + r4;
            float v = acc[r4] + bvs;
            if (RELU) v = v > 0.f ? v : 0.f;
            Yb[(size_t)node * 128 + h] = f2bf(v);
        }
    } else {
        // FOUT == 16: 8-way K-split + LDS reduce
        int ks0 = wave * 4 + (wave < 4 ? wave : 4);
        int ksn = (wave < 4) ? 5 : 4;
        f32x4 acc = (f32x4){0.f, 0.f, 0.f, 0.f};
        for (int ks = ks0; ks < ks0 + ksn; ks++) {
            short8 b = *(const short8*)(Wpack + ((size_t)ks * 64 + lane) * 8);
            short8 a = *(const short8*)&Abuf[l16][ks * 32 + quad * 8];
            acc = __builtin_amdgcn_mfma_f32_16x16x32_bf16(a, b, acc, 0, 0, 0);
        }
        __syncthreads();
        float* red = (float*)&Abuf[0][0];
#pragma unroll
        for (int r4 = 0; r4 < 4; r4++) red[(wave * 64 + lane) * 4 + r4] = acc[r4];
        __syncthreads();
        if (tid < 256) {
            int reg = tid >> 6, l = tid & 63;
            float s = 0.f;
#pragma unroll
            for (int w = 0; w < 8; w++) s += red[(w * 64 + l) * 4 + reg];
            int node = node0 + ((l >> 4) << 2) + reg;
            int h = l & 15;
            float v = s + bias[h];
            if (RELU) v = v > 0.f ? v : 0.f;
            ((float*)Yout)[(size_t)node * 16 + h] = v;
        }
    }
}

// ---------------------------------------------------------------------------
extern "C" void kernel_launch(void* const* d_in, const int* in_sizes, int n_in,
                              void* d_out, int out_size, void* d_ws, size_t ws_size,
                              hipStream_t stream) {
    const float* x  = (const float*)d_in[0];
    const int*   ei = (const int*)d_in[1];
    const int*   et = (const int*)d_in[2];
    const float* w0 = (const float*)d_in[3];
    const float* r0 = (const float*)d_in[4];
    const float* b0 = (const float*)d_in[5];
    const float* w1 = (const float*)d_in[6];
    const float* r1 = (const float*)d_in[7];
    const float* b1 = (const float*)d_in[8];
    const float* w2 = (const float*)d_in[9];
    const float* r2 = (const float*)d_in[10];
    const float* b2 = (const float*)d_in[11];

    char* wsp = (char*)d_ws;
    size_t off = 0;
    auto alloc = [&](size_t bytes) -> void* {
        void* p = wsp + off;
        off += (bytes + 255) & ~(size_t)255;
        return p;
    };

    int* cnt    = (int*)alloc((size_t)NB8 * 4);
    int* rs8    = (int*)alloc(((size_t)NB8 + 1) * 4);
    int* cursor = (int*)alloc((size_t)NB8 * 4);
    int* tsum   = (int*)alloc((size_t)SCAN_T * 4);
    int* toff   = (int*)alloc((size_t)SCAN_T * 4);
    unsigned short* csr_src = (unsigned short*)alloc((size_t)N_EDGES * 2);
    unsigned short* Wp0 = (unsigned short*)alloc((size_t)8 * KSTEPS * 64 * 8 * 2);
    unsigned short* Wp1 = (unsigned short*)alloc((size_t)8 * KSTEPS * 64 * 8 * 2);
    unsigned short* Wp2 = (unsigned short*)alloc((size_t)1 * KSTEPS * 64 * 8 * 2);
    unsigned int* Xb = (unsigned int*)alloc((size_t)N_NODES * 64 * 4);
    unsigned int* H0 = (unsigned int*)alloc((size_t)N_NODES * 64 * 4);
    unsigned int* H1 = (unsigned int*)alloc((size_t)N_NODES * 64 * 4);

    prep_kernel<<<dim3((PREP_TOTAL + 255) / 256), dim3(256), 0, stream>>>(
        x, Xb, r0, w0, Wp0, r1, w1, Wp1, r2, w2, Wp2, cnt);
    count_kernel<<<dim3((N_EDGES + 255) / 256), dim3(256), 0, stream>>>(ei, et, cnt, N_EDGES);
    scanA_kernel<<<dim3((SCAN_T + 255) / 256), dim3(256), 0, stream>>>(cnt, tsum);
    scanB_kernel<<<dim3(1), dim3(1024), 0, stream>>>(tsum, toff);
    scanC_kernel<<<dim3((SCAN_T + 255) / 256), dim3(256), 0, stream>>>(cnt, toff, rs8, cursor);
    scatter_kernel<<<dim3((N_EDGES + 255) / 256), dim3(256), 0, stream>>>(ei, et, cursor,
                                                                          csr_src, N_EDGES);

    int nblk = N_NODES / 16;   // 3125, exact
    layer_kernel<128, true ><<<dim3(nblk), dim3(512), 0, stream>>>(
        Xb, rs8, csr_src, Wp0, b0, (void*)H0);
    layer_kernel<128, true ><<<dim3(nblk), dim3(512), 0, stream>>>(
        H0, rs8, csr_src, Wp1, b1, (void*)H1);
    layer_kernel<16, false><<<dim3(nblk), dim3(512), 0, stream>>>(
        H1, rs8, csr_src, Wp2, b2, d_out);
}